// Round 1
// baseline (1071.065 us; speedup 1.0000x reference)
//
#include <hip/hip_runtime.h>
#include <math.h>

// Problem constants
#define BB 256
#define TT 1024
#define DD 128
#define LL 16
#define OO 256
#define TILE 16
#define DPAD 132     // padded row stride for [16][128] tiles (16B-aligned, 528B)
#define CPAD 20      // state chunk: 16 floats padded to 20 (80B, 16B-aligned)

// One block per batch b. 1024 threads = 16 waves (4/SIMD).
// Wave w owns outputs o in [w*16, w*16+16).
// Lane = og*16+ic: og in [0,4) selects a group of 4 outputs, ic in [0,16)
// selects i-range [ic*16, ic*16+16). Each lane holds R[i0..i0+15][o0..o0+3]
// in 64 VGPRs (guaranteed to fit: launch_bounds cap = 128).
// Per step: lane reads 16 state floats (4x ds_read_b128 from padded chunk),
// does 64 FMA, reduces partials over ic via 5 shfl_xor stages; 16 writer
// lanes/wave add agg and store new state (LDS, double-buffered).
//
// KEY CHANGE vs previous version: no global stores inside the step loop.
// __syncthreads() drains vmcnt(0), so a per-step y-store made every step
// pay a ~300-500 cycle store-ack stall across all 16 waves. Instead the
// writer lane overwrites aggt[k][o_w] (read exactly once, by itself) with
// the new state; the whole tile is flushed to y once per 16 steps with
// coalesced float4 stores, overlapped with the next tile's x staging.
__global__ __launch_bounds__(1024, 4)
void srkan_fused(const float* __restrict__ x,      // [B,T,D]
                 const float* __restrict__ subW,   // [L,D]
                 const float* __restrict__ subb,   // [L]
                 const float* __restrict__ aggW,   // [L,O]
                 const float* __restrict__ R,      // [O,O]
                 float* __restrict__ y)            // [B,T,O]
{
    const int b    = blockIdx.x;
    const int tid  = threadIdx.x;
    const int lane = tid & 63;
    const int w    = tid >> 6;     // wave 0..15
    const int og   = lane >> 4;    // 0..3
    const int ic   = lane & 15;    // 0..15

    __shared__ float sW[LL][DPAD];       // sub_W
    __shared__ float xs[TILE][DPAD];     // x tile
    __shared__ float acts[TILE][LL];     // activations
    __shared__ float aggt[TILE][OO];     // agg tile -> becomes y tile in place
    __shared__ float aggWt[OO][LL];      // aggW transposed [o][l]
    __shared__ float sbuf[2][16][CPAD];  // double-buffered state, padded chunks
    __shared__ float bias[LL];

    // ---- one-time init ----
    if (tid < 512) {                     // sub_W: 2048 floats as float4
        const int idx = tid * 4;
        const int l = idx >> 7, d = idx & 127;
        *(float4*)&sW[l][d] = *(const float4*)&subW[idx];
    }
    if (tid < LL) bias[tid] = subb[tid];
    {                                    // aggW transpose: 4096 floats
        const int idx = tid * 4;
        const int l = idx >> 8, o0 = idx & 255;
        float4 v = *(const float4*)&aggW[idx];
        aggWt[o0 + 0][l] = v.x; aggWt[o0 + 1][l] = v.y;
        aggWt[o0 + 2][l] = v.z; aggWt[o0 + 3][l] = v.w;
    }
    for (int i = tid; i < 2 * 16 * CPAD; i += 1024)   // zero state (incl pads)
        ((float*)sbuf)[i] = 0.f;

    // ---- R fragment: r[v][j] = R[ic*16+j][w*16+og*4+v] ----
    float r[4][16];
    {
        const int o0 = w * 16 + og * 4;
        const int i0 = ic * 16;
        const float* Rp = R + (size_t)i0 * OO + o0;
#pragma unroll
        for (int j = 0; j < 16; ++j) {
            float4 v = *(const float4*)(Rp + (size_t)j * OO);
            r[0][j] = v.x; r[1][j] = v.y; r[2][j] = v.z; r[3][j] = v.w;
        }
    }

    // writer bookkeeping: lanes ic<4 hold the final sum for o offset f(ic)
    const int f_ic   = 2 * (ic & 1) + ((ic >> 1) & 1);
    const bool writer = (ic < 4);
    const int o_w    = w * 16 + og * 4 + f_ic;

    __syncthreads();

    const float* xb = x + (size_t)b * TT * DD;
    float*       yb = y + (size_t)b * TT * OO;

    // y-flush indexing: each thread one float4 of the [16][256] tile
    const int cp_tt = (tid * 4) >> 8;
    const int cp_o  = (tid * 4) & 255;

    for (int t0 = 0; t0 < TT; t0 += TILE) {
        // ---- Phase 0: flush previous tile's y (stored in aggt in-place).
        // Coalesced float4; the store-ack drain happens once per tile at the
        // phase-1 barrier (which is already paying for the x staging loads).
        if (t0 > 0) {
            float4 v = *(const float4*)&aggt[cp_tt][cp_o];
            *(float4*)&yb[(size_t)(t0 - TILE + cp_tt) * OO + cp_o] = v;
        }

        // ---- Phase 1: stage x tile (2048 floats; each thread one float2) ----
        {
            const int idx = tid * 2;
            const int tt = idx >> 7, d = idx & 127;
            *(float2*)&xs[tt][d] = *(const float2*)&xb[(size_t)t0 * DD + idx];
        }
        __syncthreads();

        // ---- Phase 2: pre + activation (256 dots of 128, 4 threads/dot) ----
        {
            const int dot = tid >> 2;      // 0..255
            const int q   = tid & 3;
            const int tt  = dot >> 4, l = dot & 15;
            const float4* xv = (const float4*)&xs[tt][q * 32];
            const float4* wv = (const float4*)&sW[l][q * 32];
            float p0 = 0.f, p1 = 0.f, p2 = 0.f, p3 = 0.f;
#pragma unroll
            for (int j = 0; j < 8; ++j) {
                float4 a = xv[j], v = wv[j];
                p0 += a.x * v.x; p1 += a.y * v.y;
                p2 += a.z * v.z; p3 += a.w * v.w;
            }
            float p = (p0 + p1) + (p2 + p3);
            p += __shfl_xor(p, 1);
            p += __shfl_xor(p, 2);
            if (q == 0) {
                p += bias[l];
                float v;
                switch (l & 3) {
                    case 0:  v = tanhf(p); break;
                    case 1:  v = fmaxf(p, 0.f); break;
                    case 2:  v = 1.f / (1.f + expf(-p)); break;
                    default: v = p; break;
                }
                acts[tt][l] = v;
            }
        }
        __syncthreads();

        // ---- Phase 3: agg tile (each thread 4 (tt,o) dots of length 16) ----
        {
            const int g = tid >> 8;        // 0..3
            const int o = tid & 255;
            const float4* aw = (const float4*)&aggWt[o][0];
            float4 w0 = aw[0], w1 = aw[1], w2 = aw[2], w3 = aw[3];
#pragma unroll
            for (int kk = 0; kk < 4; ++kk) {
                const int tt = g * 4 + kk;
                const float4* av = (const float4*)&acts[tt][0];
                float4 a0 = av[0], a1 = av[1], a2 = av[2], a3 = av[3];
                float s0 = a0.x * w0.x + a0.y * w0.y + a0.z * w0.z + a0.w * w0.w;
                float s1 = a1.x * w1.x + a1.y * w1.y + a1.z * w1.z + a1.w * w1.w;
                float s2 = a2.x * w2.x + a2.y * w2.y + a2.z * w2.z + a2.w * w2.w;
                float s3 = a3.x * w3.x + a3.y * w3.y + a3.z * w3.z + a3.w * w3.w;
                aggt[tt][o] = (s0 + s1) + (s2 + s3);
            }
        }
        __syncthreads();

        // ---- Phase 4: TILE recurrence steps (NO vmem in this loop) ----
#pragma unroll 1
        for (int k = 0; k < TILE; ++k) {
            const int cur = k & 1;         // t0 is even, so (t0+k)&1 == k&1
            // state chunk: 16 floats, 4x b128, 2-way-conflict-free padding
            const float4* s4 = (const float4*)&sbuf[cur][ic][0];
            float4 s0 = s4[0], s1 = s4[1], s2 = s4[2], s3 = s4[3];
            float p0 = 0.f, p1 = 0.f, p2 = 0.f, p3 = 0.f;
#pragma unroll
            for (int j = 0; j < 4; ++j) {
                float sj = (&s0.x)[j];
                p0 += sj * r[0][j];      p1 += sj * r[1][j];
                p2 += sj * r[2][j];      p3 += sj * r[3][j];
            }
#pragma unroll
            for (int j = 0; j < 4; ++j) {
                float sj = (&s1.x)[j];
                p0 += sj * r[0][4 + j];  p1 += sj * r[1][4 + j];
                p2 += sj * r[2][4 + j];  p3 += sj * r[3][4 + j];
            }
#pragma unroll
            for (int j = 0; j < 4; ++j) {
                float sj = (&s2.x)[j];
                p0 += sj * r[0][8 + j];  p1 += sj * r[1][8 + j];
                p2 += sj * r[2][8 + j];  p3 += sj * r[3][8 + j];
            }
#pragma unroll
            for (int j = 0; j < 4; ++j) {
                float sj = (&s3.x)[j];
                p0 += sj * r[0][12 + j]; p1 += sj * r[1][12 + j];
                p2 += sj * r[2][12 + j]; p3 += sj * r[3][12 + j];
            }
            // reduce over ic (16 lanes): halving exchange, masks 1,2,4,8
            float q0, q1;
            {
                const bool e = (ic & 1) == 0;
                float a0 = e ? p0 : p2;
                float a1 = e ? p1 : p3;
                float b0 = e ? p2 : p0;
                float b1 = e ? p3 : p1;
                q0 = a0 + __shfl_xor(b0, 1);
                q1 = a1 + __shfl_xor(b1, 1);
            }
            float u;
            {
                const bool e = (ic & 2) == 0;
                float a = e ? q0 : q1;
                float c = e ? q1 : q0;
                u = a + __shfl_xor(c, 2);
            }
            u += __shfl_xor(u, 4);
            u += __shfl_xor(u, 8);
            if (writer) {
                // aggt[k][o_w] is read exactly once (by this lane, here) --
                // overwrite it in place with the new state for the tile flush.
                const float ns = u + aggt[k][o_w];
                sbuf[1 - cur][w][o_w & 15] = ns;   // o_w>>4 == w
                aggt[k][o_w] = ns;
            }
            __syncthreads();
        }
    }

    // ---- epilogue: flush the last tile's y ----
    {
        float4 v = *(const float4*)&aggt[cp_tt][cp_o];
        *(float4*)&yb[(size_t)(TT - TILE + cp_tt) * OO + cp_o] = v;
    }
}

extern "C" void kernel_launch(void* const* d_in, const int* in_sizes, int n_in,
                              void* d_out, int out_size, void* d_ws, size_t ws_size,
                              hipStream_t stream) {
    const float* x    = (const float*)d_in[0];
    const float* subW = (const float*)d_in[1];
    const float* subb = (const float*)d_in[2];
    const float* aggW = (const float*)d_in[3];
    const float* R    = (const float*)d_in[4];
    float* yp = (float*)d_out;

    srkan_fused<<<BB, 1024, 0, stream>>>(x, subW, subb, aggW, R, yp);
}

// Round 2
// 947.451 us; speedup vs baseline: 1.1305x; 1.1305x over previous
//
#include <hip/hip_runtime.h>
#include <math.h>

// Problem constants
#define BB 256
#define TT 1024
#define DD 128
#define LL 16
#define OO 256
#define TILE 16
#define DPAD 132     // padded row stride for [16][128] tiles (16B-aligned, 528B)
#define CPAD 20      // padded row: 16 floats -> 20 (80B, 16B-aligned, no 32-way banks)

// One block per batch b. 1024 threads = 16 waves (4/SIMD).
// Wave w owns outputs o in [w*16, w*16+16).
// Lane = og*16+ic: og in [0,4) selects a group of 4 outputs, ic in [0,16)
// selects i-range [ic*16, ic*16+16). Each lane holds R[i0..i0+15][o0..o0+3].
// Per step: lane reads 16 state floats (4x ds_read_b128 from padded chunk),
// does 64 FMA, reduces partials over ic via DPP (quad_perm xor1/xor2 +
// row_ror:4/8 -- all VALU, no LDS swizzles); 16 writer lanes/wave add agg
// and store new state (LDS, double-buffered) + y-tile slot in place.
//
// Round-1 counters: SQ_LDS_BANK_CONFLICT=3.04e7 == phase-3 aggWt 64B-row
// reads (32 lanes per 4-bank group); fixed by CPAD rows. Step-loop
// __shfl_xor -> ds_swizzle was ~480 LDS-pipe cyc/step + a 5-deep ~30cyc
// dependent latency chain; replaced by DPP adds (masks 4,8 legal as
// rotations because lanes ic^4k hold the same output column).
__global__ __launch_bounds__(1024, 4)
void srkan_fused(const float* __restrict__ x,      // [B,T,D]
                 const float* __restrict__ subW,   // [L,D]
                 const float* __restrict__ subb,   // [L]
                 const float* __restrict__ aggW,   // [L,O]
                 const float* __restrict__ R,      // [O,O]
                 float* __restrict__ y)            // [B,T,O]
{
    const int b    = blockIdx.x;
    const int tid  = threadIdx.x;
    const int lane = tid & 63;
    const int w    = tid >> 6;     // wave 0..15
    const int og   = lane >> 4;    // 0..3
    const int ic   = lane & 15;    // 0..15

    __shared__ float sW[LL][DPAD];       // sub_W
    __shared__ float xs[TILE][DPAD];     // x tile
    __shared__ float acts[TILE][LL];     // activations
    __shared__ float aggt[TILE][OO];     // agg tile -> becomes y tile in place
    __shared__ float aggWt[OO][CPAD];    // aggW transposed [o][l], padded rows
    __shared__ float sbuf[2][16][CPAD];  // double-buffered state, padded chunks
    __shared__ float bias[LL];

    // ---- one-time init ----
    if (tid < 512) {                     // sub_W: 2048 floats as float4
        const int idx = tid * 4;
        const int l = idx >> 7, d = idx & 127;
        *(float4*)&sW[l][d] = *(const float4*)&subW[idx];
    }
    if (tid < LL) bias[tid] = subb[tid];
    {                                    // aggW transpose: 4096 floats
        const int idx = tid * 4;
        const int l = idx >> 8, o0 = idx & 255;
        float4 v = *(const float4*)&aggW[idx];
        aggWt[o0 + 0][l] = v.x; aggWt[o0 + 1][l] = v.y;
        aggWt[o0 + 2][l] = v.z; aggWt[o0 + 3][l] = v.w;
    }
    for (int i = tid; i < 2 * 16 * CPAD; i += 1024)   // zero state (incl pads)
        ((float*)sbuf)[i] = 0.f;

    // ---- R fragment: r[v][j] = R[ic*16+j][w*16+og*4+v] ----
    float r[4][16];
    {
        const int o0 = w * 16 + og * 4;
        const int i0 = ic * 16;
        const float* Rp = R + (size_t)i0 * OO + o0;
#pragma unroll
        for (int j = 0; j < 16; ++j) {
            float4 v = *(const float4*)(Rp + (size_t)j * OO);
            r[0][j] = v.x; r[1][j] = v.y; r[2][j] = v.z; r[3][j] = v.w;
        }
    }

    // writer bookkeeping: lanes ic<4 hold the final sum for o offset f(ic)
    const int f_ic   = 2 * (ic & 1) + ((ic >> 1) & 1);
    const bool writer = (ic < 4);
    const int o_w    = w * 16 + og * 4 + f_ic;

    __syncthreads();

    const float* xb = x + (size_t)b * TT * DD;
    float*       yb = y + (size_t)b * TT * OO;

    // y-flush indexing: each thread one float4 of the [16][256] tile
    const int cp_tt = (tid * 4) >> 8;
    const int cp_o  = (tid * 4) & 255;

    for (int t0 = 0; t0 < TT; t0 += TILE) {
        // ---- Phase 0: flush previous tile's y (stored in aggt in-place).
        // Coalesced float4; store-ack drain happens once per tile at the
        // phase-1 barrier (already paying for the x staging loads).
        if (t0 > 0) {
            float4 v = *(const float4*)&aggt[cp_tt][cp_o];
            *(float4*)&yb[(size_t)(t0 - TILE + cp_tt) * OO + cp_o] = v;
        }

        // ---- Phase 1: stage x tile (2048 floats; each thread one float2) ----
        {
            const int idx = tid * 2;
            const int tt = idx >> 7, d = idx & 127;
            *(float2*)&xs[tt][d] = *(const float2*)&xb[(size_t)t0 * DD + idx];
        }
        __syncthreads();

        // ---- Phase 2: pre + activation (256 dots of 128, 4 threads/dot) ----
        {
            const int dot = tid >> 2;      // 0..255
            const int q   = tid & 3;
            const int tt  = dot >> 4, l = dot & 15;
            const float4* xv = (const float4*)&xs[tt][q * 32];
            const float4* wv = (const float4*)&sW[l][q * 32];
            float p0 = 0.f, p1 = 0.f, p2 = 0.f, p3 = 0.f;
#pragma unroll
            for (int j = 0; j < 8; ++j) {
                float4 a = xv[j], v = wv[j];
                p0 += a.x * v.x; p1 += a.y * v.y;
                p2 += a.z * v.z; p3 += a.w * v.w;
            }
            float p = (p0 + p1) + (p2 + p3);
            // quad sum via DPP (xor1, xor2 within quads)
            p += __builtin_bit_cast(float,
                __builtin_amdgcn_update_dpp(0, __builtin_bit_cast(int, p),
                                            0xB1, 0xF, 0xF, true));
            p += __builtin_bit_cast(float,
                __builtin_amdgcn_update_dpp(0, __builtin_bit_cast(int, p),
                                            0x4E, 0xF, 0xF, true));
            if (q == 0) {
                p += bias[l];
                float v;
                switch (l & 3) {
                    case 0:  v = tanhf(p); break;
                    case 1:  v = fmaxf(p, 0.f); break;
                    case 2:  v = 1.f / (1.f + expf(-p)); break;
                    default: v = p; break;
                }
                acts[tt][l] = v;
            }
        }
        __syncthreads();

        // ---- Phase 3: agg tile (each thread 4 (tt,o) dots of length 16) ----
        {
            const int g = tid >> 8;        // 0..3
            const int o = tid & 255;
            const float4* aw = (const float4*)&aggWt[o][0];
            float4 w0 = aw[0], w1 = aw[1], w2 = aw[2], w3 = aw[3];
#pragma unroll
            for (int kk = 0; kk < 4; ++kk) {
                const int tt = g * 4 + kk;
                const float4* av = (const float4*)&acts[tt][0];
                float4 a0 = av[0], a1 = av[1], a2 = av[2], a3 = av[3];
                float s0 = a0.x * w0.x + a0.y * w0.y + a0.z * w0.z + a0.w * w0.w;
                float s1 = a1.x * w1.x + a1.y * w1.y + a1.z * w1.z + a1.w * w1.w;
                float s2 = a2.x * w2.x + a2.y * w2.y + a2.z * w2.z + a2.w * w2.w;
                float s3 = a3.x * w3.x + a3.y * w3.y + a3.z * w3.z + a3.w * w3.w;
                aggt[tt][o] = (s0 + s1) + (s2 + s3);
            }
        }
        __syncthreads();

        // ---- Phase 4: TILE recurrence steps (no vmem, no LDS swizzles) ----
#pragma unroll 1
        for (int k = 0; k < TILE; ++k) {
            const int cur = k & 1;         // t0 is even, so (t0+k)&1 == k&1
            // state chunk: 16 floats, 4x b128, 2-way-conflict-free padding
            const float4* s4 = (const float4*)&sbuf[cur][ic][0];
            float4 s0 = s4[0], s1 = s4[1], s2 = s4[2], s3 = s4[3];
            float p0 = 0.f, p1 = 0.f, p2 = 0.f, p3 = 0.f;
#pragma unroll
            for (int j = 0; j < 4; ++j) {
                float sj = (&s0.x)[j];
                p0 += sj * r[0][j];      p1 += sj * r[1][j];
                p2 += sj * r[2][j];      p3 += sj * r[3][j];
            }
#pragma unroll
            for (int j = 0; j < 4; ++j) {
                float sj = (&s1.x)[j];
                p0 += sj * r[0][4 + j];  p1 += sj * r[1][4 + j];
                p2 += sj * r[2][4 + j];  p3 += sj * r[3][4 + j];
            }
#pragma unroll
            for (int j = 0; j < 4; ++j) {
                float sj = (&s2.x)[j];
                p0 += sj * r[0][8 + j];  p1 += sj * r[1][8 + j];
                p2 += sj * r[2][8 + j];  p3 += sj * r[3][8 + j];
            }
#pragma unroll
            for (int j = 0; j < 4; ++j) {
                float sj = (&s3.x)[j];
                p0 += sj * r[0][12 + j]; p1 += sj * r[1][12 + j];
                p2 += sj * r[2][12 + j]; p3 += sj * r[3][12 + j];
            }
            // reduce over ic (16 lanes) -- all DPP, no LDS:
            // masks 1,2 via quad_perm; masks 4,8 as row rotations (legal:
            // lanes ic, ic^4, ic^8, ic^12 hold partials for the SAME output
            // since f_ic depends only on ic&3, and rotation by 4/8 within
            // the row of 16 preserves the mod-4 coset).
            float q0, q1;
            {
                const bool e = (ic & 1) == 0;
                float a0 = e ? p0 : p2;
                float a1 = e ? p1 : p3;
                float b0 = e ? p2 : p0;
                float b1 = e ? p3 : p1;
                q0 = a0 + __builtin_bit_cast(float,
                    __builtin_amdgcn_update_dpp(0, __builtin_bit_cast(int, b0),
                                                0xB1, 0xF, 0xF, true));
                q1 = a1 + __builtin_bit_cast(float,
                    __builtin_amdgcn_update_dpp(0, __builtin_bit_cast(int, b1),
                                                0xB1, 0xF, 0xF, true));
            }
            float u;
            {
                const bool e = (ic & 2) == 0;
                float a = e ? q0 : q1;
                float c = e ? q1 : q0;
                u = a + __builtin_bit_cast(float,
                    __builtin_amdgcn_update_dpp(0, __builtin_bit_cast(int, c),
                                                0x4E, 0xF, 0xF, true));
            }
            u += __builtin_bit_cast(float,
                __builtin_amdgcn_update_dpp(0, __builtin_bit_cast(int, u),
                                            0x124, 0xF, 0xF, true)); // row_ror:4
            u += __builtin_bit_cast(float,
                __builtin_amdgcn_update_dpp(0, __builtin_bit_cast(int, u),
                                            0x128, 0xF, 0xF, true)); // row_ror:8
            if (writer) {
                // aggt[k][o_w] is read exactly once (by this lane, here) --
                // overwrite it in place with the new state for the tile flush.
                const float ns = u + aggt[k][o_w];
                sbuf[1 - cur][w][o_w & 15] = ns;   // o_w>>4 == w
                aggt[k][o_w] = ns;
            }
            __syncthreads();
        }
    }

    // ---- epilogue: flush the last tile's y ----
    {
        float4 v = *(const float4*)&aggt[cp_tt][cp_o];
        *(float4*)&yb[(size_t)(TT - TILE + cp_tt) * OO + cp_o] = v;
    }
}

extern "C" void kernel_launch(void* const* d_in, const int* in_sizes, int n_in,
                              void* d_out, int out_size, void* d_ws, size_t ws_size,
                              hipStream_t stream) {
    const float* x    = (const float*)d_in[0];
    const float* subW = (const float*)d_in[1];
    const float* subb = (const float*)d_in[2];
    const float* aggW = (const float*)d_in[3];
    const float* R    = (const float*)d_in[4];
    float* yp = (float*)d_out;

    srkan_fused<<<BB, 1024, 0, stream>>>(x, subW, subb, aggW, R, yp);
}

// Round 3
// 898.386 us; speedup vs baseline: 1.1922x; 1.0546x over previous
//
#include <hip/hip_runtime.h>
#include <math.h>

// Problem constants
#define BB 256
#define TT 1024
#define DD 128
#define LL 16
#define OO 256
#define TILE 16
#define DPAD 132     // padded row stride for [16][128] tiles (16B-aligned)
#define CPAD 20      // padded row: 16 floats -> 20 (80B, 16B-aligned)

// 512 threads = 8 waves (2/SIMD, VGPR cap 256).
// Wave w owns outputs [w*32, w*32+32). Lane = og*16+ic (og 0..3, ic 0..15):
// lane holds r[v][j] = R[ic*16+j][w*32+og*8+v] (128 VGPRs, fits the 256 cap
// -- the 1024-thread version's 128-cap forced this fragment into spill,
// costing ~100 extra VALU ops/lane/step per round-2 counters).
// Per step: lane reads 16 state floats (4x ds_read_b128, 16 distinct addrs
// per wave -> ~2 LDS cyc each), 128 FMA into p[0..7], reduce over 16 ic
// lanes via 3 DPP splits (xor1, xor2, xor8=row_ror:8) + 1 ds_swizzle xor4
// merge; writer lanes (ic&4==0) add agg, store new state (LDS dbuf) and
// overwrite aggt[k][o_w] in place as the y tile.
// All barriers are lgkmcnt-only (no vmem in the loop), so the x prefetch
// and y-flush stores stay in flight across step barriers.

template<int CTRL>
__device__ __forceinline__ float dpp_mov(float v) {
    return __builtin_bit_cast(float,
        __builtin_amdgcn_update_dpp(0, __builtin_bit_cast(int, v),
                                    CTRL, 0xF, 0xF, true));
}
__device__ __forceinline__ float swz_xor4(float v) {
    // BitMode: (xor<<10)|(or<<5)|and -> lane ^ 4 (guide-listed 0x101F)
    return __builtin_bit_cast(float,
        __builtin_amdgcn_ds_swizzle(__builtin_bit_cast(int, v), 0x101F));
}
__device__ __forceinline__ void bar_lds() {
    // lgkm-only barrier: step loop has no vmem, so never drain vmcnt.
    asm volatile("s_waitcnt lgkmcnt(0)" ::: "memory");
    __builtin_amdgcn_s_barrier();
}

__global__ __launch_bounds__(512, 2)
void srkan_fused(const float* __restrict__ x,      // [B,T,D]
                 const float* __restrict__ subW,   // [L,D]
                 const float* __restrict__ subb,   // [L]
                 const float* __restrict__ aggW,   // [L,O]
                 const float* __restrict__ R,      // [O,O]
                 float* __restrict__ y)            // [B,T,O]
{
    const int b    = blockIdx.x;
    const int tid  = threadIdx.x;
    const int lane = tid & 63;
    const int w    = tid >> 6;     // wave 0..7
    const int og   = lane >> 4;    // 0..3
    const int ic   = lane & 15;    // 0..15

    __shared__ float sW[LL][DPAD];       // sub_W
    __shared__ float xs[TILE][DPAD];     // x tile
    __shared__ float acts[TILE][LL];     // activations
    __shared__ float aggt[TILE][OO];     // agg tile -> becomes y tile in place
    __shared__ float aggWt[OO][CPAD];    // aggW transposed [o][l], padded
    __shared__ float sbuf[2][16][CPAD];  // double-buffered state chunks
    __shared__ float bias[LL];

    // ---- one-time init ----
    {                                    // sW: 2048 floats, one float4 each
        const int idx = tid * 4;
        const int l = idx >> 7, d = idx & 127;
        *(float4*)&sW[l][d] = *(const float4*)&subW[idx];
    }
    if (tid < LL) bias[tid] = subb[tid];
#pragma unroll
    for (int h = 0; h < 2; ++h) {        // aggW transpose: 4096 floats
        const int idx = (tid + h * 512) * 4;
        const int l = idx >> 8, o0 = idx & 255;
        float4 v = *(const float4*)&aggW[idx];
        aggWt[o0 + 0][l] = v.x; aggWt[o0 + 1][l] = v.y;
        aggWt[o0 + 2][l] = v.z; aggWt[o0 + 3][l] = v.w;
    }
    for (int i = tid; i < 2 * 16 * CPAD; i += 512)   // zero state (incl pads)
        ((float*)sbuf)[i] = 0.f;

    // ---- R fragment: r[v][j] = R[ic*16+j][w*32+og*8+v] (128 VGPRs) ----
    const int o_base = w * 32 + og * 8;
    float r[8][16];
    {
        const float* Rp = R + (size_t)(ic * 16) * OO + o_base;
#pragma unroll
        for (int j = 0; j < 16; ++j) {
            float4 lo = *(const float4*)(Rp + (size_t)j * OO);
            float4 hi = *(const float4*)(Rp + (size_t)j * OO + 4);
            r[0][j] = lo.x; r[1][j] = lo.y; r[2][j] = lo.z; r[3][j] = lo.w;
            r[4][j] = hi.x; r[5][j] = hi.y; r[6][j] = hi.z; r[7][j] = hi.w;
        }
    }

    // reduce output mapping: after splits by bits {1,2,8} lane ic holds
    // v(ic) = 4*(ic&1) + 2*((ic>>1)&1) + ((ic>>3)&1); {ic, ic^4} duplicate.
    const int v_ic   = 4 * (ic & 1) + 2 * ((ic >> 1) & 1) + ((ic >> 3) & 1);
    const bool writer = (ic & 4) == 0;
    const int o_w    = o_base + v_ic;
    const int c_w    = o_w >> 4, e_w = o_w & 15;

    bar_lds();

    const float* xb = x + (size_t)b * TT * DD;
    float*       yb = y + (size_t)b * TT * OO;

    // x prefetch: one float4/thread covers the 2048-float tile
    const int xp_tt = tid >> 5, xp_d = (tid * 4) & 127;
    float4 xpre = *(const float4*)&xb[tid * 4];     // tile 0

#pragma unroll 1
    for (int t0 = 0; t0 < TT; t0 += TILE) {
        // ---- A: flush previous tile's y (in-flight across soft barriers) --
        if (t0) {
#pragma unroll
            for (int h = 0; h < 2; ++h) {
                const int idx = h * 2048 + tid * 4;
                const int tt = idx >> 8, o = idx & 255;
                float4 v = *(const float4*)&aggt[tt][o];
                *(float4*)&yb[(size_t)(t0 - TILE + tt) * OO + o] = v;
            }
        }
        // ---- B: xs write from prefetched regs ----
        *(float4*)&xs[xp_tt][xp_d] = xpre;
        bar_lds();

        // ---- C: pre + activation (256 dots of 128, 2 threads/dot) ----
        {
            const int dot = tid >> 1, q = tid & 1;
            const int tt = dot >> 4, l = dot & 15;
            const float4* xv = (const float4*)&xs[tt][q * 64];
            const float4* wv = (const float4*)&sW[l][q * 64];
            float p0 = 0.f, p1 = 0.f, p2 = 0.f, p3 = 0.f;
#pragma unroll
            for (int j = 0; j < 16; ++j) {
                float4 a = xv[j], vv = wv[j];
                p0 += a.x * vv.x; p1 += a.y * vv.y;
                p2 += a.z * vv.z; p3 += a.w * vv.w;
            }
            float p = (p0 + p1) + (p2 + p3);
            p += dpp_mov<0xB1>(p);                    // xor1: q-pair sum
            if (q == 0) {
                p += bias[l];
                float v;
                switch (l & 3) {
                    case 0:  v = tanhf(p); break;
                    case 1:  v = fmaxf(p, 0.f); break;
                    case 2:  v = 1.f / (1.f + expf(-p)); break;
                    default: v = p; break;
                }
                acts[tt][l] = v;
            }
        }
        bar_lds();

        // ---- D: agg tile (each thread 8 (tt,o) dots of length 16) ----
        {
            const int g = tid >> 8;        // 0..1
            const int o = tid & 255;
            const float4* aw = (const float4*)&aggWt[o][0];
            float4 w0 = aw[0], w1 = aw[1], w2 = aw[2], w3 = aw[3];
#pragma unroll
            for (int kk = 0; kk < 8; ++kk) {
                const int tt = g * 8 + kk;
                const float4* av = (const float4*)&acts[tt][0];
                float4 a0 = av[0], a1 = av[1], a2 = av[2], a3 = av[3];
                float s0 = a0.x * w0.x + a0.y * w0.y + a0.z * w0.z + a0.w * w0.w;
                float s1 = a1.x * w1.x + a1.y * w1.y + a1.z * w1.z + a1.w * w1.w;
                float s2 = a2.x * w2.x + a2.y * w2.y + a2.z * w2.z + a2.w * w2.w;
                float s3 = a3.x * w3.x + a3.y * w3.y + a3.z * w3.z + a3.w * w3.w;
                aggt[tt][o] = (s0 + s1) + (s2 + s3);
            }
        }
        // prefetch next x tile; soft barriers never drain vmcnt, so this
        // load stays in flight across all 16 step barriers.
        if (t0 + TILE < TT)
            xpre = *(const float4*)&xb[(size_t)(t0 + TILE) * DD + tid * 4];
        bar_lds();

        // ---- E: TILE recurrence steps (no vmem, lgkm-only barriers) ----
#pragma unroll 2
        for (int k = 0; k < TILE; ++k) {
            const int cur = k & 1;         // t0 is even
            const float4* s4 = (const float4*)&sbuf[cur][ic][0];
            float4 s0 = s4[0], s1 = s4[1], s2 = s4[2], s3 = s4[3];
            float p[8];
#pragma unroll
            for (int v = 0; v < 8; ++v) p[v] = 0.f;
#pragma unroll
            for (int jb = 0; jb < 4; ++jb) {
                const float4 sv = (jb == 0) ? s0 : (jb == 1) ? s1
                                 : (jb == 2) ? s2 : s3;
#pragma unroll
                for (int e = 0; e < 4; ++e) {
                    const float sj = (e == 0) ? sv.x : (e == 1) ? sv.y
                                    : (e == 2) ? sv.z : sv.w;
#pragma unroll
                    for (int v = 0; v < 8; ++v)
                        p[v] += sj * r[v][jb * 4 + e];
                }
            }
            // reduce over 16 ic lanes: splits xor1, xor2, xor8(row_ror:8),
            // merge xor4 (ds_swizzle). All within the lane's 16-row.
            float q1a[4];
            {
                const bool e = (ic & 1) == 0;
#pragma unroll
                for (int m = 0; m < 4; ++m) {
                    float a  = e ? p[m] : p[4 + m];
                    float bb = e ? p[4 + m] : p[m];
                    q1a[m] = a + dpp_mov<0xB1>(bb);
                }
            }
            float q2a[2];
            {
                const bool e = (ic & 2) == 0;
#pragma unroll
                for (int m = 0; m < 2; ++m) {
                    float a  = e ? q1a[m] : q1a[2 + m];
                    float bb = e ? q1a[2 + m] : q1a[m];
                    q2a[m] = a + dpp_mov<0x4E>(bb);
                }
            }
            float u;
            {
                const bool e = (ic & 8) == 0;
                float a  = e ? q2a[0] : q2a[1];
                float bb = e ? q2a[1] : q2a[0];
                u = a + dpp_mov<0x128>(bb);    // row_ror:8 == xor8 in row16
            }
            u += swz_xor4(u);                  // merge: {ic, ic^4}
            if (writer) {
                const float ns = u + aggt[k][o_w];
                sbuf[cur ^ 1][c_w][e_w] = ns;
                aggt[k][o_w] = ns;             // in-place y tile slot
            }
            bar_lds();
        }
    }

    // ---- epilogue: flush the last tile's y ----
#pragma unroll
    for (int h = 0; h < 2; ++h) {
        const int idx = h * 2048 + tid * 4;
        const int tt = idx >> 8, o = idx & 255;
        float4 v = *(const float4*)&aggt[tt][o];
        *(float4*)&yb[(size_t)(TT - TILE + tt) * OO + o] = v;
    }
}

extern "C" void kernel_launch(void* const* d_in, const int* in_sizes, int n_in,
                              void* d_out, int out_size, void* d_ws, size_t ws_size,
                              hipStream_t stream) {
    const float* x    = (const float*)d_in[0];
    const float* subW = (const float*)d_in[1];
    const float* subb = (const float*)d_in[2];
    const float* aggW = (const float*)d_in[3];
    const float* R    = (const float*)d_in[4];
    float* yp = (float*)d_out;

    srkan_fused<<<BB, 512, 0, stream>>>(x, subW, subb, aggW, R, yp);
}

// Round 5
// 851.535 us; speedup vs baseline: 1.2578x; 1.0550x over previous
//
#include <hip/hip_runtime.h>
#include <math.h>

// Problem constants
#define BB 256
#define TT 1024
#define DD 128
#define LL 16
#define OO 256
#define TILE 16
#define DPAD 132     // padded row stride for [16][128] tiles (16B-aligned)
#define APAD 20      // acts row pad (80B, 16B-aligned)
#define CPAD 20      // state chunk pad (80B, 16B-aligned, 2-way banks = free)

// 512 threads = 8 waves (2/SIMD, VGPR cap 256).
// Wave w owns outputs [w*32, w*32+32). Lane = og*16+ic.
// Lane holds a PERMUTED R fragment as v2f pairs: r2[m][j] = {R_col(m), R_col(m+4)}
// where col(v) = o_base + c(ic ^ g(v)), c(j)=4*j0+2*j1+j3, g = {0,8,2,10,1,9,3,11}.
// This permutation (baked in at load via 3 conditional-swap layers) makes the
// per-step reduction a select-free butterfly:
//   q[m] = p2[m].x + dpp_xor1(p2[m].y)   (pair partner IS the xor1 operand)
//   t[m] = q[m]    + dpp_xor2(q[m+2])
//   u    = t[0]    + dpp_ror8(t[1])      (ror8 == xor8 within 16-rows)
//   u   += ds_swizzle_xor4(u)
// FMA core uses float2 ext-vectors -> v_pk_fma_f32 (2 MAC/instr): 64 pk_fma
// per lane per step instead of 128 v_fmac.
// Round-3 post-mortem: VGPR_Count=100 < |r|=128 -> fragment lived in AGPRs
// with per-use accvgpr_read (~128 extra VALU/step). Fixes: phase-C unroll
// capped at 4, sched_barrier(0) phase fences, aggWt LDS dropped (aggW column
// in per-thread regs; acts reads in phase D are wave-uniform broadcasts).

typedef float v2f __attribute__((ext_vector_type(2)));

template<int CTRL>
__device__ __forceinline__ float dpp_mov(float v) {
    return __builtin_bit_cast(float,
        __builtin_amdgcn_update_dpp(0, __builtin_bit_cast(int, v),
                                    CTRL, 0xF, 0xF, true));
}
__device__ __forceinline__ float swz_xor4(float v) {
    // BitMode: (xor<<10)|(or<<5)|and -> lane ^ 4
    return __builtin_bit_cast(float,
        __builtin_amdgcn_ds_swizzle(__builtin_bit_cast(int, v), 0x101F));
}
__device__ __forceinline__ void bar_lds() {
    // lgkm-only barrier: step loop has no vmem, never drain vmcnt.
    asm volatile("s_waitcnt lgkmcnt(0)" ::: "memory");
    __builtin_amdgcn_s_barrier();
}
__device__ __forceinline__ void sched_fence() {
    __builtin_amdgcn_sched_barrier(0);
}
__device__ __forceinline__ v2f mk2(float a, float b) {
    v2f r; r.x = a; r.y = b; return r;
}

__global__ __launch_bounds__(512, 2)
void srkan_fused(const float* __restrict__ x,      // [B,T,D]
                 const float* __restrict__ subW,   // [L,D]
                 const float* __restrict__ subb,   // [L]
                 const float* __restrict__ aggW,   // [L,O]
                 const float* __restrict__ R,      // [O,O]
                 float* __restrict__ y)            // [B,T,O]
{
    const int b    = blockIdx.x;
    const int tid  = threadIdx.x;
    const int lane = tid & 63;
    const int w    = tid >> 6;     // wave 0..7
    const int og   = lane >> 4;    // 0..3
    const int ic   = lane & 15;    // 0..15

    __shared__ float sW[LL][DPAD];       // sub_W
    __shared__ float xs[TILE][DPAD];     // x tile
    __shared__ float acts[TILE][APAD];   // activations (padded rows)
    __shared__ float aggt[TILE][OO];     // agg tile -> y tile in place
    __shared__ float sbuf[2][16][CPAD];  // double-buffered state chunks
    __shared__ float bias[LL];

    // ---- one-time init ----
    {                                    // sW: 2048 floats, one float4 each
        const int idx = tid * 4;
        const int l = idx >> 7, d = idx & 127;
        *(float4*)&sW[l][d] = *(const float4*)&subW[idx];
    }
    if (tid < LL) bias[tid] = subb[tid];
    for (int i = tid; i < 2 * 16 * CPAD; i += 512)
        ((float*)sbuf)[i] = 0.f;

    // aggW column in registers for phase D (o_d = tid&255, g = tid>>8)
    const int o_d = tid & 255;
    v2f aw2[8];
#pragma unroll
    for (int h = 0; h < 8; ++h)
        aw2[h] = mk2(aggW[(2 * h) * OO + o_d], aggW[(2 * h + 1) * OO + o_d]);

    // ---- permuted R fragment (v2f pairs), 128 floats -> 64 v2f regs ----
    const int o_base = w * 32 + og * 8;
    const int f0 = (ic >> 3) & 1, f1 = (ic >> 1) & 1, f2 = ic & 1;
    v2f r2[4][16];
    {
        const float* Rp = R + (size_t)(ic * 16) * OO + o_base;
#pragma unroll
        for (int j = 0; j < 16; ++j) {
            float4 lo = *(const float4*)(Rp + (size_t)j * OO);
            float4 hi = *(const float4*)(Rp + (size_t)j * OO + 4);
            // layer f1: swap 2-groups
            float l0 = f1 ? lo.z : lo.x, l1 = f1 ? lo.w : lo.y;
            float l2 = f1 ? lo.x : lo.z, l3 = f1 ? lo.y : lo.w;
            float h0 = f1 ? hi.z : hi.x, h1 = f1 ? hi.w : hi.y;
            float h2 = f1 ? hi.x : hi.z, h3 = f1 ? hi.y : hi.w;
            // layer f0: swap adjacent
            float m0 = f0 ? l1 : l0, m1 = f0 ? l0 : l1;
            float m2 = f0 ? l3 : l2, m3 = f0 ? l2 : l3;
            float n0 = f0 ? h1 : h0, n1 = f0 ? h0 : h1;
            float n2 = f0 ? h3 : h2, n3 = f0 ? h2 : h3;
            // layer f2: lo/hi swap into the (v, v+4) pair slots
            r2[0][j] = f2 ? mk2(n0, m0) : mk2(m0, n0);
            r2[1][j] = f2 ? mk2(n1, m1) : mk2(m1, n1);
            r2[2][j] = f2 ? mk2(n2, m2) : mk2(m2, n2);
            r2[3][j] = f2 ? mk2(n3, m3) : mk2(m3, n3);
        }
    }

    // writer: lanes ic&4==0; final column = o_base + c(ic)
    const bool writer = (ic & 4) == 0;
    const int o_w = o_base + 4 * f2 + 2 * f1 + f0;
    const int c_w = o_w >> 4, e_w = o_w & 15;

    bar_lds();

    const float* xb = x + (size_t)b * TT * DD;
    float*       yb = y + (size_t)b * TT * OO;

    const int xp_tt = tid >> 5, xp_d = (tid * 4) & 127;
    float4 xpre = *(const float4*)&xb[tid * 4];     // tile 0 prefetch

#pragma unroll 1
    for (int t0 = 0; t0 < TT; t0 += TILE) {
        // ---- A: flush previous tile's y (rides across soft barriers) ----
        if (t0) {
#pragma unroll
            for (int h = 0; h < 2; ++h) {
                const int idx = h * 2048 + tid * 4;
                const int tt = idx >> 8, o = idx & 255;
                float4 v = *(const float4*)&aggt[tt][o];
                *(float4*)&yb[(size_t)(t0 - TILE + tt) * OO + o] = v;
            }
        }
        // ---- B: xs write from prefetched regs ----
        *(float4*)&xs[xp_tt][xp_d] = xpre;
        bar_lds();
        sched_fence();

        // ---- C: pre + activation (256 dots of 128, 2 threads/dot) ----
        {
            const int dot = tid >> 1, q = tid & 1;
            const int tt = dot >> 4, l = dot & 15;
            const float4* xv = (const float4*)&xs[tt][q * 64];
            const float4* wv = (const float4*)&sW[l][q * 64];
            v2f acc0 = mk2(0.f, 0.f), acc1 = mk2(0.f, 0.f);
#pragma unroll 4
            for (int j = 0; j < 16; ++j) {
                float4 a = xv[j], vv = wv[j];
                acc0 = __builtin_elementwise_fma(mk2(a.x, a.y), mk2(vv.x, vv.y), acc0);
                acc1 = __builtin_elementwise_fma(mk2(a.z, a.w), mk2(vv.z, vv.w), acc1);
            }
            float p = (acc0.x + acc0.y) + (acc1.x + acc1.y);
            p += dpp_mov<0xB1>(p);                    // xor1: q-pair sum
            if (q == 0) {
                p += bias[l];
                float v;
                switch (l & 3) {
                    case 0:  v = tanhf(p); break;
                    case 1:  v = fmaxf(p, 0.f); break;
                    case 2:  v = 1.f / (1.f + expf(-p)); break;
                    default: v = p; break;
                }
                acts[tt][l] = v;
            }
        }
        sched_fence();
        bar_lds();

        // ---- D: agg tile; aw in regs, acts reads are wave-uniform ----
        {
            const int g = tid >> 8;        // 0..1
#pragma unroll
            for (int kk = 0; kk < 8; ++kk) {
                const int tt = g * 8 + kk;
                const float4* av = (const float4*)&acts[tt][0];
                float4 a0 = av[0], a1 = av[1], a2 = av[2], a3 = av[3];
                v2f acc = mk2(a0.x, a0.y) * aw2[0];
                acc = __builtin_elementwise_fma(mk2(a0.z, a0.w), aw2[1], acc);
                acc = __builtin_elementwise_fma(mk2(a1.x, a1.y), aw2[2], acc);
                acc = __builtin_elementwise_fma(mk2(a1.z, a1.w), aw2[3], acc);
                acc = __builtin_elementwise_fma(mk2(a2.x, a2.y), aw2[4], acc);
                acc = __builtin_elementwise_fma(mk2(a2.z, a2.w), aw2[5], acc);
                acc = __builtin_elementwise_fma(mk2(a3.x, a3.y), aw2[6], acc);
                acc = __builtin_elementwise_fma(mk2(a3.z, a3.w), aw2[7], acc);
                aggt[tt][o_d] = acc.x + acc.y;
            }
        }
        // prefetch next x tile (stays in flight across all step barriers)
        if (t0 + TILE < TT)
            xpre = *(const float4*)&xb[(size_t)(t0 + TILE) * DD + tid * 4];
        sched_fence();
        bar_lds();

        // ---- E: TILE recurrence steps (no vmem; 64 pk_fma + butterfly) ----
#pragma unroll 2
        for (int k = 0; k < TILE; ++k) {
            const int cur = k & 1;         // t0 is even
            const float4* s4 = (const float4*)&sbuf[cur][ic][0];
            float4 s0 = s4[0], s1 = s4[1], s2 = s4[2], s3 = s4[3];
            v2f p2[4];
            {
                const v2f sc = mk2(s0.x, s0.x);
                p2[0] = sc * r2[0][0]; p2[1] = sc * r2[1][0];
                p2[2] = sc * r2[2][0]; p2[3] = sc * r2[3][0];
            }
#pragma unroll
            for (int jb = 0; jb < 4; ++jb) {
                const float4 sv = jb == 0 ? s0 : jb == 1 ? s1 : jb == 2 ? s2 : s3;
#pragma unroll
                for (int e = 0; e < 4; ++e) {
                    if (jb == 0 && e == 0) continue;
                    const float sj = e == 0 ? sv.x : e == 1 ? sv.y
                                   : e == 2 ? sv.z : sv.w;
                    const v2f sc = mk2(sj, sj);
                    const int j = jb * 4 + e;
                    p2[0] = __builtin_elementwise_fma(sc, r2[0][j], p2[0]);
                    p2[1] = __builtin_elementwise_fma(sc, r2[1][j], p2[1]);
                    p2[2] = __builtin_elementwise_fma(sc, r2[2][j], p2[2]);
                    p2[3] = __builtin_elementwise_fma(sc, r2[3][j], p2[3]);
                }
            }
            // select-free butterfly (permutation baked into r2 load)
            float q0 = p2[0].x + dpp_mov<0xB1>(p2[0].y);
            float q1 = p2[1].x + dpp_mov<0xB1>(p2[1].y);
            float q2 = p2[2].x + dpp_mov<0xB1>(p2[2].y);
            float q3 = p2[3].x + dpp_mov<0xB1>(p2[3].y);
            float u0 = q0 + dpp_mov<0x4E>(q2);
            float u1 = q1 + dpp_mov<0x4E>(q3);
            float u  = u0 + dpp_mov<0x128>(u1);   // row_ror:8 == xor8 in row16
            u += swz_xor4(u);                      // merge {ic, ic^4}
            if (writer) {
                const float ns = u + aggt[k][o_w];
                sbuf[cur ^ 1][c_w][e_w] = ns;
                aggt[k][o_w] = ns;                 // in-place y tile slot
            }
            bar_lds();
        }
    }

    // ---- epilogue: flush the last tile's y ----
#pragma unroll
    for (int h = 0; h < 2; ++h) {
        const int idx = h * 2048 + tid * 4;
        const int tt = idx >> 8, o = idx & 255;
        float4 v = *(const float4*)&aggt[tt][o];
        *(float4*)&yb[(size_t)(TT - TILE + tt) * OO + o] = v;
    }
}

extern "C" void kernel_launch(void* const* d_in, const int* in_sizes, int n_in,
                              void* d_out, int out_size, void* d_ws, size_t ws_size,
                              hipStream_t stream) {
    const float* x    = (const float*)d_in[0];
    const float* subW = (const float*)d_in[1];
    const float* subb = (const float*)d_in[2];
    const float* aggW = (const float*)d_in[3];
    const float* R    = (const float*)d_in[4];
    float* yp = (float*)d_out;

    srkan_fused<<<BB, 512, 0, stream>>>(x, subW, subb, aggW, R, yp);
}